// Round 7
// baseline (560.765 us; speedup 1.0000x reference)
//
#include <hip/hip_runtime.h>
#include <stdint.h>

#define Bn 16
#define C 64
#define H 256
#define W 256
#define HW (H * W)          // 65536
#define NHW (Bn * HW)       // 1048576

// Fused-kernel tile geometry: 64 wide x 16 high, 512 threads, 2 px/thread.
#define TW 64
#define TH 16
#define SZH 18              // TH + 2 halo rows
#define SZW 73              // 72 used cols (gw0-4 .. gw0+67), +1 pad

typedef float f32x4 __attribute__((ext_vector_type(4)));
typedef float f32x2 __attribute__((ext_vector_type(2)));

// ---------------------------------------------------------------------------
// Kernel 1: weight prep. One wave per output channel o.
// wbitsP[o*10+tap] bit c = (w[o][c][tap] > 0)  (padded rows, 16B-aligned)
// prm[o] = {scale, pb0, aw, pb1};  edg[o] = {edgeL-192, edgeR-192}
// ---------------------------------------------------------------------------
__global__ void prep_weights(const float* __restrict__ w,
                             const float* __restrict__ pb0,
                             const float* __restrict__ aw,
                             const float* __restrict__ pb1,
                             uint64_t* __restrict__ wbitsP,
                             float4* __restrict__ prm,
                             int2* __restrict__ edg) {
    int o = blockIdx.x;     // 64 blocks
    int c = threadIdx.x;    // 64 threads = 1 wave
    const float* wp = w + ((size_t)o * C + c) * 9;
    float asum = 0.f;
    uint64_t m[9];
#pragma unroll
    for (int tap = 0; tap < 9; ++tap) {
        float v = wp[tap];
        asum += fabsf(v);
        m[tap] = __ballot(v > 0.f);   // uniform across the wave
    }
    if (c == 0) {
#pragma unroll
        for (int tap = 0; tap < 9; ++tap) wbitsP[o * 10 + tap] = m[tap];
        wbitsP[o * 10 + 9] = 0;
        edg[o] = make_int2(
            2 * (int)(__popcll(m[0]) + __popcll(m[3]) + __popcll(m[6])) - 192,
            2 * (int)(__popcll(m[2]) + __popcll(m[5]) + __popcll(m[8])) - 192);
    }
#pragma unroll
    for (int off = 32; off > 0; off >>= 1)
        asum += __shfl_down(asum, off);
    if (c == 0) prm[o] = make_float4(asum * (1.f / 576.f), pb0[o], aw[o], pb1[o]);
}

// ---------------------------------------------------------------------------
// Kernel 2 (fused): pack z (tile + 1px halo) into LDS, then binary conv +
// RPReLU + residual as a TWO-PHASE software pipeline per 8-channel group:
//   POPC  (pure VALU/SALU, no vmem)  -> packed i16x2 d-values in bank regs
//   EPI   (pure float + NT store)    -> consumes d + identity loads issued
//                                       one full POPC-group earlier (~700 in)
// Banks A/B are named static arrays (no runtime indexing -> no scratch).
// XCD-chunked block swizzle: 1024 blocks, 128/XCD contiguous -> halo rows +
// identity lines L2-shared between vertically adjacent tiles.
// Out-of-image z-words are 0; column borders via edg[] fixup in POPC; row
// borders take the masked slow path (whole waves, wave-uniform branch).
// ---------------------------------------------------------------------------
__global__ __launch_bounds__(512, 2) void bconv_fused(
        const uint64_t* __restrict__ wbitsP,
        const float4* __restrict__ prm,
        const int2* __restrict__ edg,
        const float* __restrict__ x,
        const float* __restrict__ bias,
        float* __restrict__ out) {
    __shared__ uint64_t sz[SZH * SZW];     // 10512 B

    int t = threadIdx.x;
    // XCD-chunked bijective swizzle (1024 % 8 == 0): XCD k gets logical
    // blocks [k*128, (k+1)*128) = 2 whole images, in row-major tile order.
    int bid = (blockIdx.x & 7) * 128 + (blockIdx.x >> 3);
    int n = bid >> 6;                      // image
    int tile = bid & 63;
    int ty = tile >> 2, tx = tile & 3;     // 16 down, 4 across
    int gh0 = ty * TH, gw0 = tx * TW;

    const float* xn = x + (size_t)n * C * HW;

    // ---- phase 1: pack z into LDS (18 rows x 18 four-col chunks),
    //      8x8 batched loads with next-batch prefetch -------------------------
    if (t < SZH * 18) {
        int r = t / 18;
        int cb = (t - r * 18) * 4;         // col offset within sz row
        int gh = gh0 + r - 1;
        int gwb = gw0 - 4 + cb;            // global col of chunk base (4-aligned)
        uint64_t b0 = 0, b1 = 0, b2 = 0, b3 = 0;
        if ((unsigned)gh < (unsigned)H && (unsigned)gwb <= (unsigned)(W - 4)) {
            const float* xp = xn + gh * W + gwb;
            f32x4 cur[8], nxt[8];
#pragma unroll
            for (int k = 0; k < 8; ++k)
                cur[k] = *reinterpret_cast<const f32x4*>(xp + (size_t)k * HW);
            for (int b8 = 0; b8 < 8; ++b8) {
                if (b8 < 7) {
#pragma unroll
                    for (int k = 0; k < 8; ++k)
                        nxt[k] = *reinterpret_cast<const f32x4*>(
                            xp + (size_t)((b8 + 1) * 8 + k) * HW);
                }
#pragma unroll
                for (int k = 0; k < 8; ++k) {
                    int ch = b8 * 8 + k;
                    float bc = bias[ch];   // uniform -> scalar load
                    f32x4 v = cur[k];
                    b0 |= (uint64_t)(v.x + bc > 0.f) << ch;
                    b1 |= (uint64_t)(v.y + bc > 0.f) << ch;
                    b2 |= (uint64_t)(v.z + bc > 0.f) << ch;
                    b3 |= (uint64_t)(v.w + bc > 0.f) << ch;
                }
                if (b8 < 7) {
#pragma unroll
                    for (int k = 0; k < 8; ++k) cur[k] = nxt[k];
                }
            }
        }
        uint64_t* zp = &sz[r * SZW + cb];
        zp[0] = b0; zp[1] = b1; zp[2] = b2; zp[3] = b3;
    }
    __syncthreads();

    // ---- phase 2: this thread's 3x4 z window from LDS ----------------------
    int tr = t >> 5;                       // tile row 0..15 (32 thr/row)
    int tc2 = (t & 31) * 2;                // tile col base (2 px/thread)
    int gh = gh0 + tr;
    int gw = gw0 + tc2;

    uint64_t zb[3][4];
#pragma unroll
    for (int i = 0; i < 3; ++i)
#pragma unroll
        for (int j = 0; j < 4; ++j)
            zb[i][j] = sz[(tr + i) * SZW + tc2 + 3 + j];   // col gw-1+j

    const float* xid = xn + gh * W + gw;
    float* op = out + (size_t)n * C * HW + gh * W + gw;
    bool leftE  = (gw == 0);
    bool rightE = (gw == W - 2);

    // wave-uniform row-border predicate (a wave spans 2 tile rows)
    bool slowW = (ty == 0 && tr < 2) || (ty == 15 && tr >= 14);

    if (!slowW) {
        // ---- two-bank software pipeline over 8 groups of 8 channels -------
        uint32_t dA[8], dB[8];             // packed {d1:i16, d0:i16} per o
        f32x2 idA[8], idB[8];              // identity prefetch banks

        // POPC: group gbase..gbase+7 -> dst (pure VALU/SALU, no vmem)
        auto POPC = [&](uint32_t (&dst)[8], int gbase) {
#pragma unroll
            for (int k = 0; k < 8; ++k) {
                int oc = gbase + k;
                const uint64_t* wp = wbitsP + oc * 10;   // uniform -> s_load
                int s0 = 0, s1 = 0;
#pragma unroll
                for (int i = 0; i < 3; ++i)
#pragma unroll
                    for (int jj = 0; jj < 3; ++jj) {
                        uint64_t wt = wp[i * 3 + jj];
                        s0 += (int)__popcll(wt ^ zb[i][jj]);
                        s1 += (int)__popcll(wt ^ zb[i][jj + 1]);
                    }
                int d0 = 576 - 2 * s0, d1 = 576 - 2 * s1;
                int2 e = edg[oc];                        // uniform -> s_load
                if (leftE)  d0 += e.x;
                if (rightE) d1 += e.y;
                dst[k] = (uint32_t)(d0 & 0xffff) | ((uint32_t)(d1 & 0xffff) << 16);
            }
        };
        // LOADG: issue identity loads for group gbase
        auto LOADG = [&](f32x2 (&idst)[8], int gbase) {
#pragma unroll
            for (int k = 0; k < 8; ++k)
                idst[k] = *reinterpret_cast<const f32x2*>(
                    xid + (size_t)(gbase + k) * HW);
        };
        // EPI: pure float epilogue + NT store for group gbase
        auto EPI = [&](const uint32_t (&dsrc)[8], const f32x2 (&isrc)[8],
                       int gbase) {
#pragma unroll
            for (int k = 0; k < 8; ++k) {
                int oc = gbase + k;
                float4 pr = prm[oc];                     // uniform -> s_load x4
                int d0 = (int)(short)(dsrc[k] & 0xffff);
                int d1 = (int)(short)(dsrc[k] >> 16);
                f32x2 iv = isrc[k];
                f32x2 r;
                float y;
                y = pr.x * (float)d0 + pr.y; y = y > 0.f ? y : pr.z * y;
                r.x = y + pr.w + iv.x;
                y = pr.x * (float)d1 + pr.y; y = y > 0.f ? y : pr.z * y;
                r.y = y + pr.w + iv.y;
                __builtin_nontemporal_store(
                    r, reinterpret_cast<f32x2*>(op + (size_t)oc * HW));
            }
        };

        // prologue: fill both banks
        LOADG(idA, 0);  POPC(dA, 0);
        LOADG(idB, 8);  POPC(dB, 8);
        // steady state: EPI(g) overlaps with POPC(g+2) covering loads(g+2)
        for (int g = 0; g < 48; g += 16) {
            EPI(dA, idA, g);
            LOADG(idA, g + 16);  POPC(dA, g + 16);
            EPI(dB, idB, g + 8);
            LOADG(idB, g + 24);  POPC(dB, g + 24);
        }
        EPI(dA, idA, 48);
        EPI(dB, idB, 56);
    } else {
        // masked path: exact for interior rows too (vrow all -1)
        int vrow[3], vcol[4];
#pragma unroll
        for (int i = 0; i < 3; ++i)
            vrow[i] = ((unsigned)(gh - 1 + i) < (unsigned)H) ? -1 : 0;
#pragma unroll
        for (int j = 0; j < 4; ++j)
            vcol[j] = ((unsigned)(gw - 1 + j) < (unsigned)W) ? -1 : 0;
        int nr  = (vrow[0] & 1) + (vrow[1] & 1) + (vrow[2] & 1);
        int nv0 = nr * ((vcol[0] & 1) + (vcol[1] & 1) + (vcol[2] & 1));
        int nv1 = nr * ((vcol[1] & 1) + (vcol[2] & 1) + (vcol[3] & 1));
#pragma unroll 2
        for (int o = 0; o < C; ++o) {
            const uint64_t* wp = wbitsP + o * 10;
            int s0 = 0, s1 = 0;
#pragma unroll
            for (int i = 0; i < 3; ++i)
#pragma unroll
                for (int jj = 0; jj < 3; ++jj) {
                    uint64_t wt = wp[i * 3 + jj];
                    s0 += (vrow[i] & vcol[jj])     & (int)__popcll(wt ^ zb[i][jj]);
                    s1 += (vrow[i] & vcol[jj + 1]) & (int)__popcll(wt ^ zb[i][jj + 1]);
                }
            float4 pr = prm[o];
            f32x2 idv = *reinterpret_cast<const f32x2*>(xid + (size_t)o * HW);
            f32x2 r;
            float y;
            y = pr.x * (float)(64 * nv0 - 2 * s0) + pr.y; y = y > 0.f ? y : pr.z * y; r.x = y + pr.w + idv.x;
            y = pr.x * (float)(64 * nv1 - 2 * s1) + pr.y; y = y > 0.f ? y : pr.z * y; r.y = y + pr.w + idv.y;
            __builtin_nontemporal_store(r, reinterpret_cast<f32x2*>(op + (size_t)o * HW));
        }
    }
}

// ---------------------------------------------------------------------------
extern "C" void kernel_launch(void* const* d_in, const int* in_sizes, int n_in,
                              void* d_out, int out_size, void* d_ws, size_t ws_size,
                              hipStream_t stream) {
    const float* x           = (const float*)d_in[0];
    const float* move0_bias  = (const float*)d_in[1];
    const float* conv_weight = (const float*)d_in[2];
    const float* prelu_w     = (const float*)d_in[3];
    const float* pr_bias0    = (const float*)d_in[4];
    const float* pr_bias1    = (const float*)d_in[5];
    float* out = (float*)d_out;

    uint8_t* ws = (uint8_t*)d_ws;
    uint64_t* wbitsP = (uint64_t*)ws;                    // 64*10*8 = 5120 B
    float4* prm      = (float4*)(ws + 5120);             // 1024 B (16B-aligned)
    int2* edg        = (int2*)(ws + 6144);               // 512 B

    prep_weights<<<64, 64, 0, stream>>>(conv_weight, pr_bias0, prelu_w, pr_bias1,
                                        wbitsP, prm, edg);
    bconv_fused<<<Bn * (H / TH) * (W / TW), 512, 0, stream>>>(
        wbitsP, prm, edg, x, move0_bias, out);
}